// Round 8
// baseline (604.937 us; speedup 1.0000x reference)
//
#include <hip/hip_runtime.h>
#include <math.h>

#define N_NODES 50000
#define N_EDGES 800000
#define ET (N_EDGES + N_NODES)
#define N_GRAPHS 200
#define F_INN 16
#define C_DIM 64
#define N_HEADS 4
#define HIDD 256
#define SCAN_BLOCKS ((N_NODES + 255) / 256)

typedef __attribute__((ext_vector_type(8))) short short8;
typedef __attribute__((ext_vector_type(4))) float f32x4;
typedef __attribute__((ext_vector_type(2))) float f32x2;

__device__ __forceinline__ float bf2f(ushort u) {
  return __uint_as_float(((unsigned)u) << 16);
}
__device__ __forceinline__ ushort f2bf(float f) {  // round-to-nearest-even
  unsigned u = __float_as_uint(f);
  u += 0x7fff + ((u >> 16) & 1);
  return (ushort)(u >> 16);
}

__device__ __forceinline__ f32x2 emax2(f32x2 a, f32x2 b) {
#if __has_builtin(__builtin_elementwise_max)
  return __builtin_elementwise_max(a, b);
#else
  f32x2 r;
  r.x = fmaxf(a.x, b.x);
  r.y = fmaxf(a.y, b.y);
  return r;
#endif
}

// ---------------- dual GEMM (fp32 vector path, layer 1 only: K=16)
// Cl written as bf16 (feeds edge gathers), Cr as fp32.
template<int K, int M>
__global__ __launch_bounds__(256) void gemm_dual(
    const float* __restrict__ A, const float* __restrict__ Bl,
    const float* __restrict__ Br, ushort* __restrict__ Clb,
    float* __restrict__ Cr, int nrows)
{
  __shared__ __align__(16) float As[16][64];
  __shared__ __align__(16) float Bls[16][64];
  __shared__ __align__(16) float Brs[16][64];
  int tid = threadIdx.x;
  int row0 = blockIdx.x * 64;
  int col0 = blockIdx.y * 64;
  int tr = (tid >> 4) << 2;
  int tc = (tid & 15) << 2;
  float accL[4][4] = {{0.f}}, accR[4][4] = {{0.f}};
  int arow = tid >> 2, ak = (tid & 3) << 2;
  int brow = tid >> 4, bcol = (tid & 15) << 2;
  for (int k0 = 0; k0 < K; k0 += 16) {
    float4 av = make_float4(0.f, 0.f, 0.f, 0.f);
    int gr = row0 + arow;
    if (gr < nrows) av = *(const float4*)&A[(size_t)gr * K + k0 + ak];
    As[ak + 0][arow] = av.x;
    As[ak + 1][arow] = av.y;
    As[ak + 2][arow] = av.z;
    As[ak + 3][arow] = av.w;
    *(float4*)&Bls[brow][bcol] = *(const float4*)&Bl[(size_t)(k0 + brow) * M + col0 + bcol];
    *(float4*)&Brs[brow][bcol] = *(const float4*)&Br[(size_t)(k0 + brow) * M + col0 + bcol];
    __syncthreads();
    #pragma unroll
    for (int k = 0; k < 16; ++k) {
      float4 a = *(const float4*)&As[k][tr];
      float4 bl = *(const float4*)&Bls[k][tc];
      float4 br = *(const float4*)&Brs[k][tc];
      float aa[4] = {a.x, a.y, a.z, a.w};
      float lb[4] = {bl.x, bl.y, bl.z, bl.w};
      float rb[4] = {br.x, br.y, br.z, br.w};
      #pragma unroll
      for (int ii = 0; ii < 4; ++ii)
        #pragma unroll
        for (int jj = 0; jj < 4; ++jj) {
          accL[ii][jj] = fmaf(aa[ii], lb[jj], accL[ii][jj]);
          accR[ii][jj] = fmaf(aa[ii], rb[jj], accR[ii][jj]);
        }
    }
    __syncthreads();
  }
  #pragma unroll
  for (int ii = 0; ii < 4; ++ii) {
    int gr = row0 + tr + ii;
    if (gr < nrows) {
      *(ushort4*)&Clb[(size_t)gr * M + col0 + tc] =
          make_ushort4(f2bf(accL[ii][0]), f2bf(accL[ii][1]),
                       f2bf(accL[ii][2]), f2bf(accL[ii][3]));
      *(float4*)&Cr[(size_t)gr * M + col0 + tc] =
          make_float4(accR[ii][0], accR[ii][1], accR[ii][2], accR[ii][3]);
    }
  }
}

// ---------------- bf16x2 split helpers
__device__ __forceinline__ void split_bf16(float a, ushort& hi, ushort& lo) {
  unsigned u = __float_as_uint(a);
  hi = (ushort)(u >> 16);
  float ah = __uint_as_float(u & 0xffff0000u);
  float r = a - ah;                      // exact
  lo = (ushort)(__float_as_uint(r) >> 16);
}

// ---------------- convert a weight matrix [K][N] -> [half][K/8][N][8] bf16
template<int K, int N>
__global__ void convertB(const float* __restrict__ W, ushort* __restrict__ BTmat) {
  int idx = blockIdx.x * blockDim.x + threadIdx.x;
  if (idx >= K * N) return;
  int k = idx / N, n = idx - k * N;
  ushort hi, lo;
  split_bf16(W[idx], hi, lo);
  size_t dst = ((size_t)(k >> 3) * N + n) * 8 + (k & 7);
  BTmat[dst] = hi;
  BTmat[(size_t)(K / 8) * N * 8 + dst] = lo;
}

// ---------------- fully-fused MFMA dual GEMM (K=256):
//   A' = elu(bn(H)) split to bf16 hi/lo, staged in LDS (swizzled), read once.
//   Block covers 64 rows x ALL 2N combined cols; wave w owns 64 combined cols.
//   Cl = A'@Bl written bf16; Cr = A'@Br written fp32.
template<int N>
__global__ __launch_bounds__(N * 2) void gemm_fused(
    const float* __restrict__ H, const float* __restrict__ gsum,
    const float* __restrict__ gsumsq, const float* __restrict__ g,
    const float* __restrict__ be, const ushort* __restrict__ BT,
    ushort* __restrict__ Clb, float* __restrict__ Cr)
{
  constexpr int THREADS = N * 2;
  constexpr int PLANE = 32 * N * 8;
  __shared__ float SCs[256], SHs[256];
  __shared__ ushort Ah_s[64 * 256];
  __shared__ ushort Al_s[64 * 256];
  const int tid = threadIdx.x;
  const int brow0 = blockIdx.x * 64;

  // phase 0: BN finalize in-block
  const float invn = 1.0f / (float)N_NODES;
  for (int c = tid; c < 256; c += THREADS) {
    float mu = gsum[c] * invn;
    float var = gsumsq[c] * invn - mu * mu;
    float sc = g[c] * rsqrtf(var + 1e-5f);
    SCs[c] = sc;
    SHs[c] = be[c] - mu * sc;
  }
  __syncthreads();

  // phase 1: stage A tile -> LDS, applying BN+ELU+bf16x2 split; XOR swizzle.
  for (int gid = tid; gid < 2048; gid += THREADS) {
    int r = gid >> 5;
    int ch0 = (gid & 31) * 8;
    int grow = min(brow0 + r, N_NODES - 1);
    float4 v0 = *(const float4*)&H[(size_t)grow * 256 + ch0];
    float4 v1 = *(const float4*)&H[(size_t)grow * 256 + ch0 + 4];
    float4 sc0 = *(const float4*)&SCs[ch0];
    float4 sc1 = *(const float4*)&SCs[ch0 + 4];
    float4 sh0 = *(const float4*)&SHs[ch0];
    float4 sh1 = *(const float4*)&SHs[ch0 + 4];
    float vv[8] = {v0.x, v0.y, v0.z, v0.w, v1.x, v1.y, v1.z, v1.w};
    float scv[8] = {sc0.x, sc0.y, sc0.z, sc0.w, sc1.x, sc1.y, sc1.z, sc1.w};
    float shv[8] = {sh0.x, sh0.y, sh0.z, sh0.w, sh1.x, sh1.y, sh1.z, sh1.w};
    short8 hi8, lo8;
    #pragma unroll
    for (int j = 0; j < 8; ++j) {
      float t = fmaf(vv[j], scv[j], shv[j]);
      float e = t > 0.f ? t : __expf(t) - 1.f;
      ushort h, l;
      split_bf16(e, h, l);
      hi8[j] = (short)h;
      lo8[j] = (short)l;
    }
    int off = r * 512 + ((ch0 * 2) ^ ((r & 7) << 4));
    *(short8*)((char*)Ah_s + off) = hi8;
    *(short8*)((char*)Al_s + off) = lo8;
  }
  __syncthreads();

  // phase 2: k-loop. wave -> 64 combined cols (mat = L if combc<N else R).
  const int wave = tid >> 6, lane = tid & 63;
  const int cn = lane & 15, kgrp = lane >> 4;
  const int combc = wave * 64;
  const bool isR = combc >= N;
  const ushort* Bh = BT + (isR ? 2 * PLANE : 0);
  const ushort* Bl_ = Bh + PLANE;
  const int cb = combc & (N - 1);
  f32x4 acc[4][4];
  #pragma unroll
  for (int rt = 0; rt < 4; ++rt)
    #pragma unroll
    for (int ct = 0; ct < 4; ++ct) acc[rt][ct] = (f32x4)(0.f);

  #pragma unroll 2
  for (int k0 = 0; k0 < 256; k0 += 32) {
    short8 ah[4], al[4];
    #pragma unroll
    for (int rt = 0; rt < 4; ++rt) {
      int row = rt * 16 + cn;
      int off = row * 512 + (((k0 * 2) + kgrp * 16) ^ ((row & 7) << 4));
      ah[rt] = *(const short8*)((const char*)Ah_s + off);
      al[rt] = *(const short8*)((const char*)Al_s + off);
    }
    const size_t bbase = (size_t)((k0 >> 3) + kgrp) * (N * 8);
    #pragma unroll
    for (int ct = 0; ct < 4; ++ct) {
      const size_t bo = bbase + (size_t)(cb + ct * 16 + cn) * 8;
      short8 bh = *(const short8*)&Bh[bo];
      short8 bl = *(const short8*)&Bl_[bo];
      #pragma unroll
      for (int rt = 0; rt < 4; ++rt) {
        acc[rt][ct] = __builtin_amdgcn_mfma_f32_16x16x32_bf16(ah[rt], bh, acc[rt][ct], 0, 0, 0);
        acc[rt][ct] = __builtin_amdgcn_mfma_f32_16x16x32_bf16(ah[rt], bl, acc[rt][ct], 0, 0, 0);
        acc[rt][ct] = __builtin_amdgcn_mfma_f32_16x16x32_bf16(al[rt], bh, acc[rt][ct], 0, 0, 0);
      }
    }
  }

  // epilogue: C/D layout col=lane&15, row=(lane>>4)*4+reg  [m89 verified]
  #pragma unroll
  for (int ct = 0; ct < 4; ++ct) {
    int cc = cb + ct * 16 + cn;
    #pragma unroll
    for (int rt = 0; rt < 4; ++rt) {
      int crow0 = brow0 + rt * 16 + kgrp * 4;
      #pragma unroll
      for (int j = 0; j < 4; ++j) {
        int rr = crow0 + j;
        if (rr < N_NODES) {
          if (!isR) Clb[(size_t)rr * N + cc] = f2bf(acc[rt][ct][j]);
          else      Cr[(size_t)rr * N + cc] = acc[rt][ct][j];
        }
      }
    }
  }
}

// ---------------- CSR build: histogram -> multi-block scan -> scatter
__global__ void hist_kernel(const int* __restrict__ dsts, int* __restrict__ curs) {
  int i = blockIdx.x * blockDim.x + threadIdx.x;
  if (i >= ET) return;
  int d = (i < N_EDGES) ? dsts[i] : i - N_EDGES;
  atomicAdd(&curs[d], 1);
}

__global__ __launch_bounds__(256) void scan_part(
    const int* __restrict__ curs, int* __restrict__ rows, int* __restrict__ bsum)
{
  __shared__ int tmp[256];
  int t = threadIdx.x;
  int i = blockIdx.x * 256 + t;
  int v = (i < N_NODES) ? curs[i] : 0;
  tmp[t] = v;
  __syncthreads();
  #pragma unroll
  for (int off = 1; off < 256; off <<= 1) {
    int u = (t >= off) ? tmp[t - off] : 0;
    __syncthreads();
    tmp[t] += u;
    __syncthreads();
  }
  if (i < N_NODES) rows[i] = tmp[t] - v;
  if (t == 255) bsum[blockIdx.x] = tmp[255];
}

__global__ __launch_bounds__(256) void scan_bsums(
    const int* __restrict__ bsum, int* __restrict__ boff)
{
  __shared__ int tmp[256];
  int t = threadIdx.x;
  int v = (t < SCAN_BLOCKS) ? bsum[t] : 0;
  tmp[t] = v;
  __syncthreads();
  #pragma unroll
  for (int off = 1; off < 256; off <<= 1) {
    int u = (t >= off) ? tmp[t - off] : 0;
    __syncthreads();
    tmp[t] += u;
    __syncthreads();
  }
  if (t < SCAN_BLOCKS) boff[t] = tmp[t] - v;
}

__global__ __launch_bounds__(256) void scan_apply(
    int* __restrict__ rows, const int* __restrict__ boff, int* __restrict__ curs)
{
  int i = blockIdx.x * 256 + threadIdx.x;
  if (i < N_NODES) {
    int r = rows[i] + boff[blockIdx.x];
    rows[i] = r;
    curs[i] = r;
  }
  if (i == 0) rows[N_NODES] = ET;
}

__global__ void scatter_kernel(const int* __restrict__ srcs, const int* __restrict__ dsts,
                               int* __restrict__ curs, int* __restrict__ esrc) {
  int i = blockIdx.x * blockDim.x + threadIdx.x;
  if (i >= ET) return;
  int s, d;
  if (i < N_EDGES) { s = srcs[i]; d = dsts[i]; } else { s = d = i - N_EDGES; }
  int pos = atomicAdd(&curs[d], 1);
  esrc[pos] = s;
}

// ---------------- fused flash-attention pass: one wave per dst, online softmax,
// bf16 xl gathers, packed-fp32 VALU math, 4 edges/iter with aligned int4
// index loads, register accumulator.
template<int HEADS_, int D_>
__global__ __launch_bounds__(256) void flash_csr(
    const ushort* __restrict__ xl, const float* __restrict__ xr,
    const float* __restrict__ att, const int* __restrict__ rows,
    const int* __restrict__ esrc, float* __restrict__ out)
{
  int d = blockIdx.x * 4 + (threadIdx.x >> 6);
  if (d >= N_NODES) return;
  int lane = threadIdx.x & 63;
  int beg = rows[d], end = rows[d + 1];
  if constexpr (D_ == 256) {
    float4 xrvf = *(const float4*)&xr[(size_t)d * 256 + lane * 4];
    float4 wf = *(const float4*)&att[lane * 4];
    f32x2 xr01 = {xrvf.x, xrvf.y}, xr23 = {xrvf.z, xrvf.w};
    f32x2 w01 = {wf.x, wf.y}, w23 = {wf.z, wf.w};
    float m = -INFINITY, s = 0.f;
    f32x2 a01 = {0.f, 0.f}, a23 = {0.f, 0.f};

    auto loadb = [&](int src, f32x2& ba, f32x2& bb) {
      ushort4 u = *(const ushort4*)&xl[(size_t)src * 256 + lane * 4];
      ba = f32x2{bf2f(u.x), bf2f(u.y)};
      bb = f32x2{bf2f(u.z), bf2f(u.w)};
    };
    auto scoreP = [&](f32x2 ba, f32x2 bb) -> float {
      f32x2 v01 = ba + xr01, v23 = bb + xr23;
      v01 = emax2(v01, v01 * 0.2f);      // leaky_relu == max(v, 0.2v)
      v23 = emax2(v23, v23 * 0.2f);
      f32x2 dd = v01 * w01 + v23 * w23;  // pk_mul + pk_fma
      return dd.x + dd.y;
    };
    auto one_edge = [&](int src) {
      f32x2 ba, bb;
      loadb(src, ba, bb);
      float e = scoreP(ba, bb);
      e += __shfl_xor(e, 1);
      e += __shfl_xor(e, 2);
      e += __shfl_xor(e, 4);
      e += __shfl_xor(e, 8);
      float mn = fmaxf(m, e);
      float f = __expf(m - mn);
      float pe = __expf(e - mn);
      s = s * f + pe;
      a01 = a01 * f + ba * pe;
      a23 = a23 * f + bb * pe;
      m = mn;
    };

    int p = beg;
    int head = min(end, (beg + 3) & ~3);
    for (; p < head; ++p) one_edge(esrc[p]);
    for (; p + 4 <= end; p += 4) {
      int4 sv = *(const int4*)&esrc[p];   // aligned: p % 4 == 0
      f32x2 b1a, b1b, b2a, b2b, b3a, b3b, b4a, b4b;
      loadb(sv.x, b1a, b1b);
      loadb(sv.y, b2a, b2b);
      loadb(sv.z, b3a, b3b);
      loadb(sv.w, b4a, b4b);
      float e1 = scoreP(b1a, b1b);
      float e2 = scoreP(b2a, b2b);
      float e3 = scoreP(b3a, b3b);
      float e4 = scoreP(b4a, b4b);
      e1 += __shfl_xor(e1, 1); e2 += __shfl_xor(e2, 1);
      e3 += __shfl_xor(e3, 1); e4 += __shfl_xor(e4, 1);
      e1 += __shfl_xor(e1, 2); e2 += __shfl_xor(e2, 2);
      e3 += __shfl_xor(e3, 2); e4 += __shfl_xor(e4, 2);
      e1 += __shfl_xor(e1, 4); e2 += __shfl_xor(e2, 4);
      e3 += __shfl_xor(e3, 4); e4 += __shfl_xor(e4, 4);
      e1 += __shfl_xor(e1, 8); e2 += __shfl_xor(e2, 8);
      e3 += __shfl_xor(e3, 8); e4 += __shfl_xor(e4, 8);
      float mn = fmaxf(fmaxf(m, fmaxf(e1, e2)), fmaxf(e3, e4));
      float f = __expf(m - mn);
      float p1 = __expf(e1 - mn);
      float p2 = __expf(e2 - mn);
      float p3 = __expf(e3 - mn);
      float p4 = __expf(e4 - mn);
      s = s * f + ((p1 + p2) + (p3 + p4));
      f32x2 t01 = b1a * p1 + b2a * p2;
      f32x2 u01 = b3a * p3 + b4a * p4;
      a01 = a01 * f + (t01 + u01);
      f32x2 t23 = b1b * p1 + b2b * p2;
      f32x2 u23 = b3b * p3 + b4b * p4;
      a23 = a23 * f + (t23 + u23);
      m = mn;
    }
    for (; p < end; ++p) one_edge(esrc[p]);

    float inv = 1.f / (s + 1e-16f);
    *(float4*)&out[(size_t)d * 256 + lane * 4] =
        make_float4(a01.x * inv, a01.y * inv, a23.x * inv, a23.y * inv);
  } else {  // 1 head, D=64
    float xrv = xr[(size_t)d * 64 + lane];
    float w = att[lane];
    float m = -INFINITY, s = 0.f, acc = 0.f;
    int p = beg;
    for (; p + 2 <= end; p += 2) {
      int s1 = esrc[p], s2 = esrc[p + 1];
      float b1 = bf2f(xl[(size_t)s1 * 64 + lane]);
      float b2 = bf2f(xl[(size_t)s2 * 64 + lane]);
      float v1 = b1 + xrv, v2 = b2 + xrv;
      v1 = fmaxf(v1, 0.2f * v1);
      v2 = fmaxf(v2, 0.2f * v2);
      float e1 = v1 * w, e2 = v2 * w;
      e1 += __shfl_xor(e1, 1);  e2 += __shfl_xor(e2, 1);
      e1 += __shfl_xor(e1, 2);  e2 += __shfl_xor(e2, 2);
      e1 += __shfl_xor(e1, 4);  e2 += __shfl_xor(e2, 4);
      e1 += __shfl_xor(e1, 8);  e2 += __shfl_xor(e2, 8);
      e1 += __shfl_xor(e1, 16); e2 += __shfl_xor(e2, 16);
      e1 += __shfl_xor(e1, 32); e2 += __shfl_xor(e2, 32);
      float mn = fmaxf(m, fmaxf(e1, e2));
      float f = __expf(m - mn);
      float p1 = __expf(e1 - mn);
      float p2 = __expf(e2 - mn);
      s = fmaf(s, f, p1 + p2);
      acc = fmaf(acc, f, fmaf(p1, b1, p2 * b2));
      m = mn;
    }
    if (p < end) {
      int s1 = esrc[p];
      float b1 = bf2f(xl[(size_t)s1 * 64 + lane]);
      float v1 = b1 + xrv;
      v1 = fmaxf(v1, 0.2f * v1);
      float e1 = v1 * w;
      e1 += __shfl_xor(e1, 1);
      e1 += __shfl_xor(e1, 2);
      e1 += __shfl_xor(e1, 4);
      e1 += __shfl_xor(e1, 8);
      e1 += __shfl_xor(e1, 16);
      e1 += __shfl_xor(e1, 32);
      float mn = fmaxf(m, e1);
      float f = __expf(m - mn);
      float p1 = __expf(e1 - mn);
      s = fmaf(s, f, p1);
      acc = fmaf(acc, f, p1 * b1);
    }
    out[(size_t)d * 64 + lane] = acc / (s + 1e-16f);
  }
}

// ---------------- BN statistics (per-channel sum / sumsq)
template<int D_, int RPB>
__global__ __launch_bounds__(256) void bn_stats(const float* __restrict__ h,
    float* __restrict__ gsum, float* __restrict__ gsumsq, int nrows)
{
  constexpr int RG = 256 / D_;
  int c = threadIdx.x % D_;
  int rg = threadIdx.x / D_;
  int r0 = blockIdx.x * RPB;
  float s = 0.f, sq = 0.f;
  int rend = min(r0 + RPB, nrows);
  for (int r = r0 + rg; r < rend; r += RG) {
    float v = h[(size_t)r * D_ + c];
    s += v;
    sq = fmaf(v, v, sq);
  }
  atomicAdd(&gsum[c], s);
  atomicAdd(&gsumsq[c], sq);
}

// ---------------- fused pooling (BN finalize+apply inline) + classifier MLP.
__global__ __launch_bounds__(256) void pool_mlp(
    const float* __restrict__ h3, const int* __restrict__ batch,
    const float* __restrict__ gsum, const float* __restrict__ gsumsq,
    const float* __restrict__ g3, const float* __restrict__ be3,
    const float* __restrict__ Wc1, const float* __restrict__ bc1,
    const float* __restrict__ Wc2, const float* __restrict__ bc2,
    float* __restrict__ outp)
{
  int g = blockIdx.x;
  int t = threadIdx.x;
  int lane = t & 63, w = t >> 6;
  int lo, hi;
  {
    int a = 0, b = N_NODES;
    while (a < b) { int mid = (a + b) >> 1; if (batch[mid] < g) a = mid + 1; else b = mid; }
    lo = a;
    b = N_NODES;
    while (a < b) { int mid = (a + b) >> 1; if (batch[mid] < g + 1) a = mid + 1; else b = mid; }
    hi = a;
  }
  const float invn = 1.0f / (float)N_NODES;
  float mu = gsum[lane] * invn;
  float var = gsumsq[lane] * invn - mu * mu;
  float scl = g3[lane] * rsqrtf(var + 1e-5f);
  float shf = be3[lane] - mu * scl;
  float s = 0.f, mx = -INFINITY;
  for (int r = lo + w; r < hi; r += 4) {
    float v = fmaf(h3[(size_t)r * 64 + lane], scl, shf);
    s += v;
    mx = fmaxf(mx, v);
  }
  __shared__ float ssum[4][64];
  __shared__ float smax[4][64];
  __shared__ float pooled[128];
  ssum[w][lane] = s;
  smax[w][lane] = mx;
  __syncthreads();
  if (w == 0) {
    float tot = ssum[0][lane] + ssum[1][lane] + ssum[2][lane] + ssum[3][lane];
    float m4 = fmaxf(fmaxf(smax[0][lane], smax[1][lane]),
                     fmaxf(smax[2][lane], smax[3][lane]));
    float cnt = (float)(hi - lo);
    pooled[lane] = tot / fmaxf(cnt, 1.f);
    pooled[64 + lane] = m4;
  }
  __syncthreads();
  if (w == 0) {
    float a = bc1[lane];
    #pragma unroll 8
    for (int k = 0; k < 128; ++k) a = fmaf(pooled[k], Wc1[k * 64 + lane], a);
    a = fmaxf(a, 0.f);
    float v = a * Wc2[lane];
    v += __shfl_xor(v, 1);
    v += __shfl_xor(v, 2);
    v += __shfl_xor(v, 4);
    v += __shfl_xor(v, 8);
    v += __shfl_xor(v, 16);
    v += __shfl_xor(v, 32);
    if (lane == 0) outp[g] = v + bc2[0];
  }
}

extern "C" void kernel_launch(void* const* d_in, const int* in_sizes, int n_in,
                              void* d_out, int out_size, void* d_ws, size_t ws_size,
                              hipStream_t stream)
{
  const float* x    = (const float*)d_in[0];
  const int*   ei   = (const int*)d_in[1];
  const int*   batch= (const int*)d_in[2];
  const float* Wl1  = (const float*)d_in[3];
  const float* Wr1  = (const float*)d_in[4];
  const float* att1 = (const float*)d_in[5];
  // b1/b2/b3 cancel in the following BatchNorm -> unused
  const float* g1   = (const float*)d_in[7];
  const float* be1  = (const float*)d_in[8];
  const float* Wl2  = (const float*)d_in[9];
  const float* Wr2  = (const float*)d_in[10];
  const float* att2 = (const float*)d_in[11];
  const float* g2   = (const float*)d_in[13];
  const float* be2  = (const float*)d_in[14];
  const float* Wl3  = (const float*)d_in[15];
  const float* Wr3  = (const float*)d_in[16];
  const float* att3 = (const float*)d_in[17];
  const float* g3   = (const float*)d_in[19];
  const float* be3  = (const float*)d_in[20];
  const float* Wc1  = (const float*)d_in[21];
  const float* bc1  = (const float*)d_in[22];
  const float* Wc2  = (const float*)d_in[23];
  const float* bc2  = (const float*)d_in[24];

  const int* srcs = ei;
  const int* dsts = ei + N_EDGES;

  float* ws = (float*)d_ws;
  size_t o = 0;
  ushort* XLB = (ushort*)(ws + o); o += (size_t)N_NODES * HIDD / 2;  // bf16 xl
  float* XR = ws + o;            o += (size_t)N_NODES * HIDD;
  float* Hb = ws + o;            o += (size_t)N_NODES * HIDD;
  ushort* BT2 = (ushort*)(ws + o); o += (size_t)4 * 32 * 256 * 8 / 2;   // 2 mats x 2 halves
  ushort* BT3 = (ushort*)(ws + o); o += (size_t)4 * 32 * 64 * 8 / 2;
  int* ESRC = (int*)(ws + o);    o += ET;
  int* ROWS = (int*)(ws + o);    o += N_NODES + 1;
  int* CURS = (int*)(ws + o);    o += N_NODES;
  int* BSUM = (int*)(ws + o);    o += SCAN_BLOCKS;
  int* BOFF = (int*)(ws + o);    o += SCAN_BLOCKS;
  float* GS  = ws + o;           o += 256;
  float* GSQ = ws + o;           o += 256;

  const int ROW_BLOCKS = (N_NODES + 63) / 64;
  const int DST_BLOCKS = (N_NODES + 3) / 4;
  constexpr int PLANE2 = 32 * 256 * 8;
  constexpr int PLANE3 = 32 * 64 * 8;

  // ================= weight transpose/split (independent; run once up front)
  convertB<256, 256><<<(65536 + 255) / 256, 256, 0, stream>>>(Wl2, BT2);
  convertB<256, 256><<<(65536 + 255) / 256, 256, 0, stream>>>(Wr2, BT2 + 2 * PLANE2);
  convertB<256, 64><<<(16384 + 255) / 256, 256, 0, stream>>>(Wl3, BT3);
  convertB<256, 64><<<(16384 + 255) / 256, 256, 0, stream>>>(Wr3, BT3 + 2 * PLANE3);

  // ================= CSR build (reused by all 3 layers) =================
  hipMemsetAsync(CURS, 0, N_NODES * 4, stream);
  hist_kernel<<<(ET + 255) / 256, 256, 0, stream>>>(dsts, CURS);
  scan_part<<<SCAN_BLOCKS, 256, 0, stream>>>(CURS, ROWS, BSUM);
  scan_bsums<<<1, 256, 0, stream>>>(BSUM, BOFF);
  scan_apply<<<SCAN_BLOCKS, 256, 0, stream>>>(ROWS, BOFF, CURS);
  scatter_kernel<<<(ET + 255) / 256, 256, 0, stream>>>(srcs, dsts, CURS, ESRC);

  // ================= layer 1 (16 -> 4x64, concat): fp32 vector GEMM ======
  gemm_dual<16, 256><<<dim3(ROW_BLOCKS, 4), 256, 0, stream>>>(
      x, Wl1, Wr1, XLB, XR, N_NODES);
  flash_csr<4, 256><<<DST_BLOCKS, 256, 0, stream>>>(XLB, XR, att1, ROWS, ESRC, Hb);
  hipMemsetAsync(GS, 0, 512 * 4, stream);
  bn_stats<256, 64><<<ROW_BLOCKS, 256, 0, stream>>>(Hb, GS, GSQ, N_NODES);

  // ================= layer 2 (256 -> 4x64): fully-fused BN+ELU+MFMA GEMM ==
  gemm_fused<256><<<ROW_BLOCKS, 512, 0, stream>>>(
      Hb, GS, GSQ, g1, be1, BT2, XLB, XR);
  flash_csr<4, 256><<<DST_BLOCKS, 256, 0, stream>>>(XLB, XR, att2, ROWS, ESRC, Hb);
  hipMemsetAsync(GS, 0, 512 * 4, stream);
  bn_stats<256, 64><<<ROW_BLOCKS, 256, 0, stream>>>(Hb, GS, GSQ, N_NODES);

  // ================= layer 3 (256 -> 64, 1 head): fused MFMA GEMM ========
  gemm_fused<64><<<ROW_BLOCKS, 128, 0, stream>>>(
      Hb, GS, GSQ, g2, be2, BT3, XLB, XR);
  flash_csr<1, 64><<<DST_BLOCKS, 256, 0, stream>>>(XLB, XR, att3, ROWS, ESRC, Hb);
  hipMemsetAsync(GS, 0, 512 * 4, stream);
  bn_stats<64, 256><<<(N_NODES + 255) / 256, 256, 0, stream>>>(Hb, GS, GSQ, N_NODES);

  // ================= fused pooling (BN inline) + classifier ==============
  pool_mlp<<<N_GRAPHS, 256, 0, stream>>>(Hb, batch, GS, GSQ, g3, be3,
                                         Wc1, bc1, Wc2, bc2, (float*)d_out);
}

// Round 9
// 577.763 us; speedup vs baseline: 1.0470x; 1.0470x over previous
//
#include <hip/hip_runtime.h>
#include <math.h>

#define N_NODES 50000
#define N_EDGES 800000
#define ET (N_EDGES + N_NODES)
#define N_GRAPHS 200
#define F_INN 16
#define C_DIM 64
#define N_HEADS 4
#define HIDD 256
#define SCAN_BLOCKS ((N_NODES + 255) / 256)

typedef __attribute__((ext_vector_type(8))) short short8;
typedef __attribute__((ext_vector_type(8))) ushort ushort8;
typedef __attribute__((ext_vector_type(4))) float f32x4;
typedef __attribute__((ext_vector_type(2))) float f32x2;

__device__ __forceinline__ float bf2f(ushort u) {
  return __uint_as_float(((unsigned)u) << 16);
}
__device__ __forceinline__ ushort f2bf(float f) {  // round-to-nearest-even
  unsigned u = __float_as_uint(f);
  u += 0x7fff + ((u >> 16) & 1);
  return (ushort)(u >> 16);
}

__device__ __forceinline__ f32x2 emax2(f32x2 a, f32x2 b) {
#if __has_builtin(__builtin_elementwise_max)
  return __builtin_elementwise_max(a, b);
#else
  f32x2 r;
  r.x = fmaxf(a.x, b.x);
  r.y = fmaxf(a.y, b.y);
  return r;
#endif
}

// ---------------- dual GEMM (fp32 vector path, layer 1 only: K=16)
// Cl written as bf16 (feeds edge gathers), Cr as fp32.
template<int K, int M>
__global__ __launch_bounds__(256) void gemm_dual(
    const float* __restrict__ A, const float* __restrict__ Bl,
    const float* __restrict__ Br, ushort* __restrict__ Clb,
    float* __restrict__ Cr, int nrows)
{
  __shared__ __align__(16) float As[16][64];
  __shared__ __align__(16) float Bls[16][64];
  __shared__ __align__(16) float Brs[16][64];
  int tid = threadIdx.x;
  int row0 = blockIdx.x * 64;
  int col0 = blockIdx.y * 64;
  int tr = (tid >> 4) << 2;
  int tc = (tid & 15) << 2;
  float accL[4][4] = {{0.f}}, accR[4][4] = {{0.f}};
  int arow = tid >> 2, ak = (tid & 3) << 2;
  int brow = tid >> 4, bcol = (tid & 15) << 2;
  for (int k0 = 0; k0 < K; k0 += 16) {
    float4 av = make_float4(0.f, 0.f, 0.f, 0.f);
    int gr = row0 + arow;
    if (gr < nrows) av = *(const float4*)&A[(size_t)gr * K + k0 + ak];
    As[ak + 0][arow] = av.x;
    As[ak + 1][arow] = av.y;
    As[ak + 2][arow] = av.z;
    As[ak + 3][arow] = av.w;
    *(float4*)&Bls[brow][bcol] = *(const float4*)&Bl[(size_t)(k0 + brow) * M + col0 + bcol];
    *(float4*)&Brs[brow][bcol] = *(const float4*)&Br[(size_t)(k0 + brow) * M + col0 + bcol];
    __syncthreads();
    #pragma unroll
    for (int k = 0; k < 16; ++k) {
      float4 a = *(const float4*)&As[k][tr];
      float4 bl = *(const float4*)&Bls[k][tc];
      float4 br = *(const float4*)&Brs[k][tc];
      float aa[4] = {a.x, a.y, a.z, a.w};
      float lb[4] = {bl.x, bl.y, bl.z, bl.w};
      float rb[4] = {br.x, br.y, br.z, br.w};
      #pragma unroll
      for (int ii = 0; ii < 4; ++ii)
        #pragma unroll
        for (int jj = 0; jj < 4; ++jj) {
          accL[ii][jj] = fmaf(aa[ii], lb[jj], accL[ii][jj]);
          accR[ii][jj] = fmaf(aa[ii], rb[jj], accR[ii][jj]);
        }
    }
    __syncthreads();
  }
  #pragma unroll
  for (int ii = 0; ii < 4; ++ii) {
    int gr = row0 + tr + ii;
    if (gr < nrows) {
      *(ushort4*)&Clb[(size_t)gr * M + col0 + tc] =
          make_ushort4(f2bf(accL[ii][0]), f2bf(accL[ii][1]),
                       f2bf(accL[ii][2]), f2bf(accL[ii][3]));
      *(float4*)&Cr[(size_t)gr * M + col0 + tc] =
          make_float4(accR[ii][0], accR[ii][1], accR[ii][2], accR[ii][3]);
    }
  }
}

// ---------------- bf16x2 split helpers
__device__ __forceinline__ void split_bf16(float a, ushort& hi, ushort& lo) {
  unsigned u = __float_as_uint(a);
  hi = (ushort)(u >> 16);
  float ah = __uint_as_float(u & 0xffff0000u);
  float r = a - ah;                      // exact
  lo = (ushort)(__float_as_uint(r) >> 16);
}

// ---------------- convert a weight matrix [K][N] -> [half][K/8][N][8] bf16
template<int K, int N>
__global__ void convertB(const float* __restrict__ W, ushort* __restrict__ BTmat) {
  int idx = blockIdx.x * blockDim.x + threadIdx.x;
  if (idx >= K * N) return;
  int k = idx / N, n = idx - k * N;
  ushort hi, lo;
  split_bf16(W[idx], hi, lo);
  size_t dst = ((size_t)(k >> 3) * N + n) * 8 + (k & 7);
  BTmat[dst] = hi;
  BTmat[(size_t)(K / 8) * N * 8 + dst] = lo;
}

// ---------------- fully-fused MFMA dual GEMM (K=256):
//   A' = elu(bn(H)) split to bf16 hi/lo, staged in LDS (swizzled), read once.
//   Block covers 64 rows x ALL 2N combined cols; wave w owns 64 combined cols.
//   Cl = A'@Bl written bf16; Cr = A'@Br written fp32.
template<int N>
__global__ __launch_bounds__(N * 2) void gemm_fused(
    const float* __restrict__ H, const float* __restrict__ gsum,
    const float* __restrict__ gsumsq, const float* __restrict__ g,
    const float* __restrict__ be, const ushort* __restrict__ BT,
    ushort* __restrict__ Clb, float* __restrict__ Cr)
{
  constexpr int THREADS = N * 2;
  constexpr int PLANE = 32 * N * 8;
  __shared__ float SCs[256], SHs[256];
  __shared__ ushort Ah_s[64 * 256];
  __shared__ ushort Al_s[64 * 256];
  const int tid = threadIdx.x;
  const int brow0 = blockIdx.x * 64;

  // phase 0: BN finalize in-block
  const float invn = 1.0f / (float)N_NODES;
  for (int c = tid; c < 256; c += THREADS) {
    float mu = gsum[c] * invn;
    float var = gsumsq[c] * invn - mu * mu;
    float sc = g[c] * rsqrtf(var + 1e-5f);
    SCs[c] = sc;
    SHs[c] = be[c] - mu * sc;
  }
  __syncthreads();

  // phase 1: stage A tile -> LDS, applying BN+ELU+bf16x2 split; XOR swizzle.
  for (int gid = tid; gid < 2048; gid += THREADS) {
    int r = gid >> 5;
    int ch0 = (gid & 31) * 8;
    int grow = min(brow0 + r, N_NODES - 1);
    float4 v0 = *(const float4*)&H[(size_t)grow * 256 + ch0];
    float4 v1 = *(const float4*)&H[(size_t)grow * 256 + ch0 + 4];
    float4 sc0 = *(const float4*)&SCs[ch0];
    float4 sc1 = *(const float4*)&SCs[ch0 + 4];
    float4 sh0 = *(const float4*)&SHs[ch0];
    float4 sh1 = *(const float4*)&SHs[ch0 + 4];
    float vv[8] = {v0.x, v0.y, v0.z, v0.w, v1.x, v1.y, v1.z, v1.w};
    float scv[8] = {sc0.x, sc0.y, sc0.z, sc0.w, sc1.x, sc1.y, sc1.z, sc1.w};
    float shv[8] = {sh0.x, sh0.y, sh0.z, sh0.w, sh1.x, sh1.y, sh1.z, sh1.w};
    short8 hi8, lo8;
    #pragma unroll
    for (int j = 0; j < 8; ++j) {
      float t = fmaf(vv[j], scv[j], shv[j]);
      float e = t > 0.f ? t : __expf(t) - 1.f;
      ushort h, l;
      split_bf16(e, h, l);
      hi8[j] = (short)h;
      lo8[j] = (short)l;
    }
    int off = r * 512 + ((ch0 * 2) ^ ((r & 7) << 4));
    *(short8*)((char*)Ah_s + off) = hi8;
    *(short8*)((char*)Al_s + off) = lo8;
  }
  __syncthreads();

  // phase 2: k-loop. wave -> 64 combined cols (mat = L if combc<N else R).
  const int wave = tid >> 6, lane = tid & 63;
  const int cn = lane & 15, kgrp = lane >> 4;
  const int combc = wave * 64;
  const bool isR = combc >= N;
  const ushort* Bh = BT + (isR ? 2 * PLANE : 0);
  const ushort* Bl_ = Bh + PLANE;
  const int cb = combc & (N - 1);
  f32x4 acc[4][4];
  #pragma unroll
  for (int rt = 0; rt < 4; ++rt)
    #pragma unroll
    for (int ct = 0; ct < 4; ++ct) acc[rt][ct] = (f32x4)(0.f);

  #pragma unroll 2
  for (int k0 = 0; k0 < 256; k0 += 32) {
    short8 ah[4], al[4];
    #pragma unroll
    for (int rt = 0; rt < 4; ++rt) {
      int row = rt * 16 + cn;
      int off = row * 512 + (((k0 * 2) + kgrp * 16) ^ ((row & 7) << 4));
      ah[rt] = *(const short8*)((const char*)Ah_s + off);
      al[rt] = *(const short8*)((const char*)Al_s + off);
    }
    const size_t bbase = (size_t)((k0 >> 3) + kgrp) * (N * 8);
    #pragma unroll
    for (int ct = 0; ct < 4; ++ct) {
      const size_t bo = bbase + (size_t)(cb + ct * 16 + cn) * 8;
      short8 bh = *(const short8*)&Bh[bo];
      short8 bl = *(const short8*)&Bl_[bo];
      #pragma unroll
      for (int rt = 0; rt < 4; ++rt) {
        acc[rt][ct] = __builtin_amdgcn_mfma_f32_16x16x32_bf16(ah[rt], bh, acc[rt][ct], 0, 0, 0);
        acc[rt][ct] = __builtin_amdgcn_mfma_f32_16x16x32_bf16(ah[rt], bl, acc[rt][ct], 0, 0, 0);
        acc[rt][ct] = __builtin_amdgcn_mfma_f32_16x16x32_bf16(al[rt], bh, acc[rt][ct], 0, 0, 0);
      }
    }
  }

  // epilogue: C/D layout col=lane&15, row=(lane>>4)*4+reg  [m89 verified]
  #pragma unroll
  for (int ct = 0; ct < 4; ++ct) {
    int cc = cb + ct * 16 + cn;
    #pragma unroll
    for (int rt = 0; rt < 4; ++rt) {
      int crow0 = brow0 + rt * 16 + kgrp * 4;
      #pragma unroll
      for (int j = 0; j < 4; ++j) {
        int rr = crow0 + j;
        if (rr < N_NODES) {
          if (!isR) Clb[(size_t)rr * N + cc] = f2bf(acc[rt][ct][j]);
          else      Cr[(size_t)rr * N + cc] = acc[rt][ct][j];
        }
      }
    }
  }
}

// ---------------- CSR build: histogram -> multi-block scan -> scatter
__global__ void hist_kernel(const int* __restrict__ dsts, int* __restrict__ curs) {
  int i = blockIdx.x * blockDim.x + threadIdx.x;
  if (i >= ET) return;
  int d = (i < N_EDGES) ? dsts[i] : i - N_EDGES;
  atomicAdd(&curs[d], 1);
}

__global__ __launch_bounds__(256) void scan_part(
    const int* __restrict__ curs, int* __restrict__ rows, int* __restrict__ bsum)
{
  __shared__ int tmp[256];
  int t = threadIdx.x;
  int i = blockIdx.x * 256 + t;
  int v = (i < N_NODES) ? curs[i] : 0;
  tmp[t] = v;
  __syncthreads();
  #pragma unroll
  for (int off = 1; off < 256; off <<= 1) {
    int u = (t >= off) ? tmp[t - off] : 0;
    __syncthreads();
    tmp[t] += u;
    __syncthreads();
  }
  if (i < N_NODES) rows[i] = tmp[t] - v;
  if (t == 255) bsum[blockIdx.x] = tmp[255];
}

__global__ __launch_bounds__(256) void scan_bsums(
    const int* __restrict__ bsum, int* __restrict__ boff)
{
  __shared__ int tmp[256];
  int t = threadIdx.x;
  int v = (t < SCAN_BLOCKS) ? bsum[t] : 0;
  tmp[t] = v;
  __syncthreads();
  #pragma unroll
  for (int off = 1; off < 256; off <<= 1) {
    int u = (t >= off) ? tmp[t - off] : 0;
    __syncthreads();
    tmp[t] += u;
    __syncthreads();
  }
  if (t < SCAN_BLOCKS) boff[t] = tmp[t] - v;
}

__global__ __launch_bounds__(256) void scan_apply(
    int* __restrict__ rows, const int* __restrict__ boff, int* __restrict__ curs)
{
  int i = blockIdx.x * 256 + threadIdx.x;
  if (i < N_NODES) {
    int r = rows[i] + boff[blockIdx.x];
    rows[i] = r;
    curs[i] = r;
  }
  if (i == 0) rows[N_NODES] = ET;
}

__global__ void scatter_kernel(const int* __restrict__ srcs, const int* __restrict__ dsts,
                               int* __restrict__ curs, int* __restrict__ esrc) {
  int i = blockIdx.x * blockDim.x + threadIdx.x;
  if (i >= ET) return;
  int s, d;
  if (i < N_EDGES) { s = srcs[i]; d = dsts[i]; } else { s = d = i - N_EDGES; }
  int pos = atomicAdd(&curs[d], 1);
  esrc[pos] = s;
}

// ---------------- flash pass, D=256 (4 heads): 32 lanes per dst (8 ch each,
// 16B gathers), 2 dsts per wave -> 2 independent gather streams per instr.
__global__ __launch_bounds__(256) void flash256(
    const ushort* __restrict__ xl, const float* __restrict__ xr,
    const float* __restrict__ att, const int* __restrict__ rows,
    const int* __restrict__ esrc, float* __restrict__ out)
{
  const int wave = threadIdx.x >> 6, lane = threadIdx.x & 63;
  const int half = lane >> 5, sl = lane & 31;
  const int d = blockIdx.x * 8 + wave * 2 + half;   // N_NODES % 8 == 0
  const int ch = sl * 8;
  float4 xa = *(const float4*)&xr[(size_t)d * 256 + ch];
  float4 xb = *(const float4*)&xr[(size_t)d * 256 + ch + 4];
  float4 wa = *(const float4*)&att[ch];
  float4 wb = *(const float4*)&att[ch + 4];
  f32x2 xr0 = {xa.x, xa.y}, xr1 = {xa.z, xa.w}, xr2 = {xb.x, xb.y}, xr3 = {xb.z, xb.w};
  f32x2 w0 = {wa.x, wa.y}, w1 = {wa.z, wa.w}, w2 = {wb.x, wb.y}, w3 = {wb.z, wb.w};
  int beg = rows[d], end = rows[d + 1];
  float m = -INFINITY, s = 0.f;
  f32x2 a0 = {0.f, 0.f}, a1 = {0.f, 0.f}, a2 = {0.f, 0.f}, a3 = {0.f, 0.f};

  auto loadb = [&](int src, f32x2 b[4]) {
    ushort8 u = *(const ushort8*)&xl[(size_t)src * 256 + ch];
    b[0] = f32x2{bf2f(u[0]), bf2f(u[1])};
    b[1] = f32x2{bf2f(u[2]), bf2f(u[3])};
    b[2] = f32x2{bf2f(u[4]), bf2f(u[5])};
    b[3] = f32x2{bf2f(u[6]), bf2f(u[7])};
  };
  auto scoreP = [&](const f32x2 b[4]) -> float {
    f32x2 v0 = b[0] + xr0, v1 = b[1] + xr1, v2 = b[2] + xr2, v3 = b[3] + xr3;
    v0 = emax2(v0, v0 * 0.2f);
    v1 = emax2(v1, v1 * 0.2f);
    v2 = emax2(v2, v2 * 0.2f);
    v3 = emax2(v3, v3 * 0.2f);
    f32x2 dd = (v0 * w0 + v1 * w1) + (v2 * w2 + v3 * w3);
    return dd.x + dd.y;
  };
  auto one_edge = [&](int src) {
    f32x2 b[4];
    loadb(src, b);
    float e = scoreP(b);
    e += __shfl_xor(e, 1);
    e += __shfl_xor(e, 2);
    e += __shfl_xor(e, 4);
    float mn = fmaxf(m, e);
    float f = __expf(m - mn);
    float pe = __expf(e - mn);
    s = s * f + pe;
    a0 = a0 * f + b[0] * pe;
    a1 = a1 * f + b[1] * pe;
    a2 = a2 * f + b[2] * pe;
    a3 = a3 * f + b[3] * pe;
    m = mn;
  };

  int p = beg;
  int hd = min(end, (beg + 3) & ~3);
  for (; p < hd; ++p) one_edge(esrc[p]);
  for (; p + 4 <= end; p += 4) {
    int4 sv = *(const int4*)&esrc[p];   // aligned: p % 4 == 0
    f32x2 b1[4], b2[4], b3[4], b4[4];
    loadb(sv.x, b1);
    loadb(sv.y, b2);
    loadb(sv.z, b3);
    loadb(sv.w, b4);
    float e1 = scoreP(b1);
    float e2 = scoreP(b2);
    float e3 = scoreP(b3);
    float e4 = scoreP(b4);
    e1 += __shfl_xor(e1, 1); e2 += __shfl_xor(e2, 1);
    e3 += __shfl_xor(e3, 1); e4 += __shfl_xor(e4, 1);
    e1 += __shfl_xor(e1, 2); e2 += __shfl_xor(e2, 2);
    e3 += __shfl_xor(e3, 2); e4 += __shfl_xor(e4, 2);
    e1 += __shfl_xor(e1, 4); e2 += __shfl_xor(e2, 4);
    e3 += __shfl_xor(e3, 4); e4 += __shfl_xor(e4, 4);
    float mn = fmaxf(fmaxf(m, fmaxf(e1, e2)), fmaxf(e3, e4));
    float f = __expf(m - mn);
    float p1 = __expf(e1 - mn);
    float p2 = __expf(e2 - mn);
    float p3 = __expf(e3 - mn);
    float p4 = __expf(e4 - mn);
    s = s * f + ((p1 + p2) + (p3 + p4));
    a0 = a0 * f + ((b1[0] * p1 + b2[0] * p2) + (b3[0] * p3 + b4[0] * p4));
    a1 = a1 * f + ((b1[1] * p1 + b2[1] * p2) + (b3[1] * p3 + b4[1] * p4));
    a2 = a2 * f + ((b1[2] * p1 + b2[2] * p2) + (b3[2] * p3 + b4[2] * p4));
    a3 = a3 * f + ((b1[3] * p1 + b2[3] * p2) + (b3[3] * p3 + b4[3] * p4));
    m = mn;
  }
  for (; p < end; ++p) one_edge(esrc[p]);

  float inv = 1.f / (s + 1e-16f);
  *(float4*)&out[(size_t)d * 256 + ch] =
      make_float4(a0.x * inv, a0.y * inv, a1.x * inv, a1.y * inv);
  *(float4*)&out[(size_t)d * 256 + ch + 4] =
      make_float4(a2.x * inv, a2.y * inv, a3.x * inv, a3.y * inv);
}

// ---------------- flash pass, D=64 (1 head): 8 lanes per dst (8 ch each,
// 16B gathers), 8 dsts per wave.
__global__ __launch_bounds__(256) void flash64(
    const ushort* __restrict__ xl, const float* __restrict__ xr,
    const float* __restrict__ att, const int* __restrict__ rows,
    const int* __restrict__ esrc, float* __restrict__ out)
{
  const int wave = threadIdx.x >> 6, lane = threadIdx.x & 63;
  const int di = lane >> 3, sl = lane & 7;
  const int d = blockIdx.x * 32 + wave * 8 + di;
  const bool valid = d < N_NODES;
  const int dc = valid ? d : N_NODES - 1;
  const int ch = sl * 8;
  float4 xa = *(const float4*)&xr[(size_t)dc * 64 + ch];
  float4 xb = *(const float4*)&xr[(size_t)dc * 64 + ch + 4];
  float4 wa = *(const float4*)&att[ch];
  float4 wb = *(const float4*)&att[ch + 4];
  f32x2 xr0 = {xa.x, xa.y}, xr1 = {xa.z, xa.w}, xr2 = {xb.x, xb.y}, xr3 = {xb.z, xb.w};
  f32x2 w0 = {wa.x, wa.y}, w1 = {wa.z, wa.w}, w2 = {wb.x, wb.y}, w3 = {wb.z, wb.w};
  int beg = rows[dc], end = rows[dc + 1];
  float m = -INFINITY, s = 0.f;
  f32x2 a0 = {0.f, 0.f}, a1 = {0.f, 0.f}, a2 = {0.f, 0.f}, a3 = {0.f, 0.f};

  auto loadb = [&](int src, f32x2 b[4]) {
    ushort8 u = *(const ushort8*)&xl[(size_t)src * 64 + ch];
    b[0] = f32x2{bf2f(u[0]), bf2f(u[1])};
    b[1] = f32x2{bf2f(u[2]), bf2f(u[3])};
    b[2] = f32x2{bf2f(u[4]), bf2f(u[5])};
    b[3] = f32x2{bf2f(u[6]), bf2f(u[7])};
  };
  auto scoreP = [&](const f32x2 b[4]) -> float {
    f32x2 v0 = b[0] + xr0, v1 = b[1] + xr1, v2 = b[2] + xr2, v3 = b[3] + xr3;
    v0 = emax2(v0, v0 * 0.2f);
    v1 = emax2(v1, v1 * 0.2f);
    v2 = emax2(v2, v2 * 0.2f);
    v3 = emax2(v3, v3 * 0.2f);
    f32x2 dd = (v0 * w0 + v1 * w1) + (v2 * w2 + v3 * w3);
    return dd.x + dd.y;
  };
  auto one_edge = [&](int src) {
    f32x2 b[4];
    loadb(src, b);
    float e = scoreP(b);
    e += __shfl_xor(e, 1);
    e += __shfl_xor(e, 2);
    e += __shfl_xor(e, 4);
    float mn = fmaxf(m, e);
    float f = __expf(m - mn);
    float pe = __expf(e - mn);
    s = s * f + pe;
    a0 = a0 * f + b[0] * pe;
    a1 = a1 * f + b[1] * pe;
    a2 = a2 * f + b[2] * pe;
    a3 = a3 * f + b[3] * pe;
    m = mn;
  };

  int p = beg;
  int hd = min(end, (beg + 3) & ~3);
  for (; p < hd; ++p) one_edge(esrc[p]);
  for (; p + 4 <= end; p += 4) {
    int4 sv = *(const int4*)&esrc[p];
    f32x2 b1[4], b2[4], b3[4], b4[4];
    loadb(sv.x, b1);
    loadb(sv.y, b2);
    loadb(sv.z, b3);
    loadb(sv.w, b4);
    float e1 = scoreP(b1);
    float e2 = scoreP(b2);
    float e3 = scoreP(b3);
    float e4 = scoreP(b4);
    e1 += __shfl_xor(e1, 1); e2 += __shfl_xor(e2, 1);
    e3 += __shfl_xor(e3, 1); e4 += __shfl_xor(e4, 1);
    e1 += __shfl_xor(e1, 2); e2 += __shfl_xor(e2, 2);
    e3 += __shfl_xor(e3, 2); e4 += __shfl_xor(e4, 2);
    e1 += __shfl_xor(e1, 4); e2 += __shfl_xor(e2, 4);
    e3 += __shfl_xor(e3, 4); e4 += __shfl_xor(e4, 4);
    float mn = fmaxf(fmaxf(m, fmaxf(e1, e2)), fmaxf(e3, e4));
    float f = __expf(m - mn);
    float p1 = __expf(e1 - mn);
    float p2 = __expf(e2 - mn);
    float p3 = __expf(e3 - mn);
    float p4 = __expf(e4 - mn);
    s = s * f + ((p1 + p2) + (p3 + p4));
    a0 = a0 * f + ((b1[0] * p1 + b2[0] * p2) + (b3[0] * p3 + b4[0] * p4));
    a1 = a1 * f + ((b1[1] * p1 + b2[1] * p2) + (b3[1] * p3 + b4[1] * p4));
    a2 = a2 * f + ((b1[2] * p1 + b2[2] * p2) + (b3[2] * p3 + b4[2] * p4));
    a3 = a3 * f + ((b1[3] * p1 + b2[3] * p2) + (b3[3] * p3 + b4[3] * p4));
    m = mn;
  }
  for (; p < end; ++p) one_edge(esrc[p]);

  if (valid) {
    float inv = 1.f / (s + 1e-16f);
    *(float4*)&out[(size_t)d * 64 + ch] =
        make_float4(a0.x * inv, a0.y * inv, a1.x * inv, a1.y * inv);
    *(float4*)&out[(size_t)d * 64 + ch + 4] =
        make_float4(a2.x * inv, a2.y * inv, a3.x * inv, a3.y * inv);
  }
}

// ---------------- BN statistics (per-channel sum / sumsq)
template<int D_, int RPB>
__global__ __launch_bounds__(256) void bn_stats(const float* __restrict__ h,
    float* __restrict__ gsum, float* __restrict__ gsumsq, int nrows)
{
  constexpr int RG = 256 / D_;
  int c = threadIdx.x % D_;
  int rg = threadIdx.x / D_;
  int r0 = blockIdx.x * RPB;
  float s = 0.f, sq = 0.f;
  int rend = min(r0 + RPB, nrows);
  for (int r = r0 + rg; r < rend; r += RG) {
    float v = h[(size_t)r * D_ + c];
    s += v;
    sq = fmaf(v, v, sq);
  }
  atomicAdd(&gsum[c], s);
  atomicAdd(&gsumsq[c], sq);
}

// ---------------- fused pooling (BN finalize+apply inline) + classifier MLP.
__global__ __launch_bounds__(256) void pool_mlp(
    const float* __restrict__ h3, const int* __restrict__ batch,
    const float* __restrict__ gsum, const float* __restrict__ gsumsq,
    const float* __restrict__ g3, const float* __restrict__ be3,
    const float* __restrict__ Wc1, const float* __restrict__ bc1,
    const float* __restrict__ Wc2, const float* __restrict__ bc2,
    float* __restrict__ outp)
{
  int g = blockIdx.x;
  int t = threadIdx.x;
  int lane = t & 63, w = t >> 6;
  int lo, hi;
  {
    int a = 0, b = N_NODES;
    while (a < b) { int mid = (a + b) >> 1; if (batch[mid] < g) a = mid + 1; else b = mid; }
    lo = a;
    b = N_NODES;
    while (a < b) { int mid = (a + b) >> 1; if (batch[mid] < g + 1) a = mid + 1; else b = mid; }
    hi = a;
  }
  const float invn = 1.0f / (float)N_NODES;
  float mu = gsum[lane] * invn;
  float var = gsumsq[lane] * invn - mu * mu;
  float scl = g3[lane] * rsqrtf(var + 1e-5f);
  float shf = be3[lane] - mu * scl;
  float s = 0.f, mx = -INFINITY;
  for (int r = lo + w; r < hi; r += 4) {
    float v = fmaf(h3[(size_t)r * 64 + lane], scl, shf);
    s += v;
    mx = fmaxf(mx, v);
  }
  __shared__ float ssum[4][64];
  __shared__ float smax[4][64];
  __shared__ float pooled[128];
  ssum[w][lane] = s;
  smax[w][lane] = mx;
  __syncthreads();
  if (w == 0) {
    float tot = ssum[0][lane] + ssum[1][lane] + ssum[2][lane] + ssum[3][lane];
    float m4 = fmaxf(fmaxf(smax[0][lane], smax[1][lane]),
                     fmaxf(smax[2][lane], smax[3][lane]));
    float cnt = (float)(hi - lo);
    pooled[lane] = tot / fmaxf(cnt, 1.f);
    pooled[64 + lane] = m4;
  }
  __syncthreads();
  if (w == 0) {
    float a = bc1[lane];
    #pragma unroll 8
    for (int k = 0; k < 128; ++k) a = fmaf(pooled[k], Wc1[k * 64 + lane], a);
    a = fmaxf(a, 0.f);
    float v = a * Wc2[lane];
    v += __shfl_xor(v, 1);
    v += __shfl_xor(v, 2);
    v += __shfl_xor(v, 4);
    v += __shfl_xor(v, 8);
    v += __shfl_xor(v, 16);
    v += __shfl_xor(v, 32);
    if (lane == 0) outp[g] = v + bc2[0];
  }
}

extern "C" void kernel_launch(void* const* d_in, const int* in_sizes, int n_in,
                              void* d_out, int out_size, void* d_ws, size_t ws_size,
                              hipStream_t stream)
{
  const float* x    = (const float*)d_in[0];
  const int*   ei   = (const int*)d_in[1];
  const int*   batch= (const int*)d_in[2];
  const float* Wl1  = (const float*)d_in[3];
  const float* Wr1  = (const float*)d_in[4];
  const float* att1 = (const float*)d_in[5];
  // b1/b2/b3 cancel in the following BatchNorm -> unused
  const float* g1   = (const float*)d_in[7];
  const float* be1  = (const float*)d_in[8];
  const float* Wl2  = (const float*)d_in[9];
  const float* Wr2  = (const float*)d_in[10];
  const float* att2 = (const float*)d_in[11];
  const float* g2   = (const float*)d_in[13];
  const float* be2  = (const float*)d_in[14];
  const float* Wl3  = (const float*)d_in[15];
  const float* Wr3  = (const float*)d_in[16];
  const float* att3 = (const float*)d_in[17];
  const float* g3   = (const float*)d_in[19];
  const float* be3  = (const float*)d_in[20];
  const float* Wc1  = (const float*)d_in[21];
  const float* bc1  = (const float*)d_in[22];
  const float* Wc2  = (const float*)d_in[23];
  const float* bc2  = (const float*)d_in[24];

  const int* srcs = ei;
  const int* dsts = ei + N_EDGES;

  float* ws = (float*)d_ws;
  size_t o = 0;
  ushort* XLB = (ushort*)(ws + o); o += (size_t)N_NODES * HIDD / 2;  // bf16 xl
  float* XR = ws + o;            o += (size_t)N_NODES * HIDD;
  float* Hb = ws + o;            o += (size_t)N_NODES * HIDD;
  ushort* BT2 = (ushort*)(ws + o); o += (size_t)4 * 32 * 256 * 8 / 2;   // 2 mats x 2 halves
  ushort* BT3 = (ushort*)(ws + o); o += (size_t)4 * 32 * 64 * 8 / 2;
  int* ESRC = (int*)(ws + o);    o += ET;
  int* ROWS = (int*)(ws + o);    o += N_NODES + 1;
  int* CURS = (int*)(ws + o);    o += N_NODES;
  int* BSUM = (int*)(ws + o);    o += SCAN_BLOCKS;
  int* BOFF = (int*)(ws + o);    o += SCAN_BLOCKS;
  float* GS  = ws + o;           o += 256;
  float* GSQ = ws + o;           o += 256;

  const int ROW_BLOCKS = (N_NODES + 63) / 64;
  constexpr int PLANE2 = 32 * 256 * 8;
  constexpr int PLANE3 = 32 * 64 * 8;

  // ================= weight transpose/split (independent; run once up front)
  convertB<256, 256><<<(65536 + 255) / 256, 256, 0, stream>>>(Wl2, BT2);
  convertB<256, 256><<<(65536 + 255) / 256, 256, 0, stream>>>(Wr2, BT2 + 2 * PLANE2);
  convertB<256, 64><<<(16384 + 255) / 256, 256, 0, stream>>>(Wl3, BT3);
  convertB<256, 64><<<(16384 + 255) / 256, 256, 0, stream>>>(Wr3, BT3 + 2 * PLANE3);

  // ================= CSR build (reused by all 3 layers) =================
  hipMemsetAsync(CURS, 0, N_NODES * 4, stream);
  hist_kernel<<<(ET + 255) / 256, 256, 0, stream>>>(dsts, CURS);
  scan_part<<<SCAN_BLOCKS, 256, 0, stream>>>(CURS, ROWS, BSUM);
  scan_bsums<<<1, 256, 0, stream>>>(BSUM, BOFF);
  scan_apply<<<SCAN_BLOCKS, 256, 0, stream>>>(ROWS, BOFF, CURS);
  scatter_kernel<<<(ET + 255) / 256, 256, 0, stream>>>(srcs, dsts, CURS, ESRC);

  // ================= layer 1 (16 -> 4x64, concat): fp32 vector GEMM ======
  gemm_dual<16, 256><<<dim3(ROW_BLOCKS, 4), 256, 0, stream>>>(
      x, Wl1, Wr1, XLB, XR, N_NODES);
  flash256<<<N_NODES / 8, 256, 0, stream>>>(XLB, XR, att1, ROWS, ESRC, Hb);
  hipMemsetAsync(GS, 0, 512 * 4, stream);
  bn_stats<256, 64><<<ROW_BLOCKS, 256, 0, stream>>>(Hb, GS, GSQ, N_NODES);

  // ================= layer 2 (256 -> 4x64): fully-fused BN+ELU+MFMA GEMM ==
  gemm_fused<256><<<ROW_BLOCKS, 512, 0, stream>>>(
      Hb, GS, GSQ, g1, be1, BT2, XLB, XR);
  flash256<<<N_NODES / 8, 256, 0, stream>>>(XLB, XR, att2, ROWS, ESRC, Hb);
  hipMemsetAsync(GS, 0, 512 * 4, stream);
  bn_stats<256, 64><<<ROW_BLOCKS, 256, 0, stream>>>(Hb, GS, GSQ, N_NODES);

  // ================= layer 3 (256 -> 64, 1 head): fused MFMA GEMM ========
  gemm_fused<64><<<ROW_BLOCKS, 128, 0, stream>>>(
      Hb, GS, GSQ, g2, be2, BT3, XLB, XR);
  flash64<<<(N_NODES + 31) / 32, 256, 0, stream>>>(XLB, XR, att3, ROWS, ESRC, Hb);
  hipMemsetAsync(GS, 0, 512 * 4, stream);
  bn_stats<64, 256><<<(N_NODES + 255) / 256, 256, 0, stream>>>(Hb, GS, GSQ, N_NODES);

  // ================= fused pooling (BN inline) + classifier ==============
  pool_mlp<<<N_GRAPHS, 256, 0, stream>>>(Hb, batch, GS, GSQ, g3, be3,
                                         Wc1, bc1, Wc2, bc2, (float*)d_out);
}

// Round 10
// 548.002 us; speedup vs baseline: 1.1039x; 1.0543x over previous
//
#include <hip/hip_runtime.h>
#include <math.h>

#define N_NODES 50000
#define N_EDGES 800000
#define ET (N_EDGES + N_NODES)
#define N_GRAPHS 200
#define F_INN 16
#define C_DIM 64
#define N_HEADS 4
#define HIDD 256
#define SCAN_BLOCKS ((N_NODES + 255) / 256)

typedef __attribute__((ext_vector_type(8))) short short8;
typedef __attribute__((ext_vector_type(8))) ushort ushort8;
typedef __attribute__((ext_vector_type(4))) float f32x4;
typedef __attribute__((ext_vector_type(2))) float f32x2;

__device__ __forceinline__ float bf2f(ushort u) {
  return __uint_as_float(((unsigned)u) << 16);
}
__device__ __forceinline__ ushort f2bf(float f) {  // round-to-nearest-even
  unsigned u = __float_as_uint(f);
  u += 0x7fff + ((u >> 16) & 1);
  return (ushort)(u >> 16);
}

__device__ __forceinline__ f32x2 emax2(f32x2 a, f32x2 b) {
#if __has_builtin(__builtin_elementwise_max)
  return __builtin_elementwise_max(a, b);
#else
  f32x2 r;
  r.x = fmaxf(a.x, b.x);
  r.y = fmaxf(a.y, b.y);
  return r;
#endif
}

// ---------------- dual GEMM (fp32 vector path, layer 1 only: K=16)
// Both outputs written bf16 (Cl feeds gathers, Cr feeds scores).
template<int K, int M>
__global__ __launch_bounds__(256) void gemm_dual(
    const float* __restrict__ A, const float* __restrict__ Bl,
    const float* __restrict__ Br, ushort* __restrict__ Clb,
    ushort* __restrict__ Crb, int nrows)
{
  __shared__ __align__(16) float As[16][64];
  __shared__ __align__(16) float Bls[16][64];
  __shared__ __align__(16) float Brs[16][64];
  int tid = threadIdx.x;
  int row0 = blockIdx.x * 64;
  int col0 = blockIdx.y * 64;
  int tr = (tid >> 4) << 2;
  int tc = (tid & 15) << 2;
  float accL[4][4] = {{0.f}}, accR[4][4] = {{0.f}};
  int arow = tid >> 2, ak = (tid & 3) << 2;
  int brow = tid >> 4, bcol = (tid & 15) << 2;
  for (int k0 = 0; k0 < K; k0 += 16) {
    float4 av = make_float4(0.f, 0.f, 0.f, 0.f);
    int gr = row0 + arow;
    if (gr < nrows) av = *(const float4*)&A[(size_t)gr * K + k0 + ak];
    As[ak + 0][arow] = av.x;
    As[ak + 1][arow] = av.y;
    As[ak + 2][arow] = av.z;
    As[ak + 3][arow] = av.w;
    *(float4*)&Bls[brow][bcol] = *(const float4*)&Bl[(size_t)(k0 + brow) * M + col0 + bcol];
    *(float4*)&Brs[brow][bcol] = *(const float4*)&Br[(size_t)(k0 + brow) * M + col0 + bcol];
    __syncthreads();
    #pragma unroll
    for (int k = 0; k < 16; ++k) {
      float4 a = *(const float4*)&As[k][tr];
      float4 bl = *(const float4*)&Bls[k][tc];
      float4 br = *(const float4*)&Brs[k][tc];
      float aa[4] = {a.x, a.y, a.z, a.w};
      float lb[4] = {bl.x, bl.y, bl.z, bl.w};
      float rb[4] = {br.x, br.y, br.z, br.w};
      #pragma unroll
      for (int ii = 0; ii < 4; ++ii)
        #pragma unroll
        for (int jj = 0; jj < 4; ++jj) {
          accL[ii][jj] = fmaf(aa[ii], lb[jj], accL[ii][jj]);
          accR[ii][jj] = fmaf(aa[ii], rb[jj], accR[ii][jj]);
        }
    }
    __syncthreads();
  }
  #pragma unroll
  for (int ii = 0; ii < 4; ++ii) {
    int gr = row0 + tr + ii;
    if (gr < nrows) {
      *(ushort4*)&Clb[(size_t)gr * M + col0 + tc] =
          make_ushort4(f2bf(accL[ii][0]), f2bf(accL[ii][1]),
                       f2bf(accL[ii][2]), f2bf(accL[ii][3]));
      *(ushort4*)&Crb[(size_t)gr * M + col0 + tc] =
          make_ushort4(f2bf(accR[ii][0]), f2bf(accR[ii][1]),
                       f2bf(accR[ii][2]), f2bf(accR[ii][3]));
    }
  }
}

// ---------------- bf16x2 split helpers
__device__ __forceinline__ void split_bf16(float a, ushort& hi, ushort& lo) {
  unsigned u = __float_as_uint(a);
  hi = (ushort)(u >> 16);
  float ah = __uint_as_float(u & 0xffff0000u);
  float r = a - ah;                      // exact
  lo = (ushort)(__float_as_uint(r) >> 16);
}

// ---------------- convert a weight matrix [K][N] -> [half][K/8][N][8] bf16
template<int K, int N>
__global__ void convertB(const float* __restrict__ W, ushort* __restrict__ BTmat) {
  int idx = blockIdx.x * blockDim.x + threadIdx.x;
  if (idx >= K * N) return;
  int k = idx / N, n = idx - k * N;
  ushort hi, lo;
  split_bf16(W[idx], hi, lo);
  size_t dst = ((size_t)(k >> 3) * N + n) * 8 + (k & 7);
  BTmat[dst] = hi;
  BTmat[(size_t)(K / 8) * N * 8 + dst] = lo;
}

// ---------------- fully-fused MFMA dual GEMM (K=256):
//   A' = elu(bn(H)) split to bf16 hi/lo, staged in LDS (swizzled), read once.
//   Block covers 64 rows x ALL 2N combined cols; wave w owns 64 combined cols.
//   Cl = A'@Bl written bf16; Cr = A'@Br written bf16 (scores only).
template<int N>
__global__ __launch_bounds__(N * 2) void gemm_fused(
    const float* __restrict__ H, const float* __restrict__ gsum,
    const float* __restrict__ gsumsq, const float* __restrict__ g,
    const float* __restrict__ be, const ushort* __restrict__ BT,
    ushort* __restrict__ Clb, ushort* __restrict__ Crb)
{
  constexpr int THREADS = N * 2;
  constexpr int PLANE = 32 * N * 8;
  __shared__ float SCs[256], SHs[256];
  __shared__ ushort Ah_s[64 * 256];
  __shared__ ushort Al_s[64 * 256];
  const int tid = threadIdx.x;
  const int brow0 = blockIdx.x * 64;

  // phase 0: BN finalize in-block
  const float invn = 1.0f / (float)N_NODES;
  for (int c = tid; c < 256; c += THREADS) {
    float mu = gsum[c] * invn;
    float var = gsumsq[c] * invn - mu * mu;
    float sc = g[c] * rsqrtf(var + 1e-5f);
    SCs[c] = sc;
    SHs[c] = be[c] - mu * sc;
  }
  __syncthreads();

  // phase 1: stage A tile -> LDS, applying BN+ELU+bf16x2 split; XOR swizzle.
  for (int gid = tid; gid < 2048; gid += THREADS) {
    int r = gid >> 5;
    int ch0 = (gid & 31) * 8;
    int grow = min(brow0 + r, N_NODES - 1);
    float4 v0 = *(const float4*)&H[(size_t)grow * 256 + ch0];
    float4 v1 = *(const float4*)&H[(size_t)grow * 256 + ch0 + 4];
    float4 sc0 = *(const float4*)&SCs[ch0];
    float4 sc1 = *(const float4*)&SCs[ch0 + 4];
    float4 sh0 = *(const float4*)&SHs[ch0];
    float4 sh1 = *(const float4*)&SHs[ch0 + 4];
    float vv[8] = {v0.x, v0.y, v0.z, v0.w, v1.x, v1.y, v1.z, v1.w};
    float scv[8] = {sc0.x, sc0.y, sc0.z, sc0.w, sc1.x, sc1.y, sc1.z, sc1.w};
    float shv[8] = {sh0.x, sh0.y, sh0.z, sh0.w, sh1.x, sh1.y, sh1.z, sh1.w};
    short8 hi8, lo8;
    #pragma unroll
    for (int j = 0; j < 8; ++j) {
      float t = fmaf(vv[j], scv[j], shv[j]);
      float e = t > 0.f ? t : __expf(t) - 1.f;
      ushort h, l;
      split_bf16(e, h, l);
      hi8[j] = (short)h;
      lo8[j] = (short)l;
    }
    int off = r * 512 + ((ch0 * 2) ^ ((r & 7) << 4));
    *(short8*)((char*)Ah_s + off) = hi8;
    *(short8*)((char*)Al_s + off) = lo8;
  }
  __syncthreads();

  // phase 2: k-loop. wave -> 64 combined cols (mat = L if combc<N else R).
  const int wave = tid >> 6, lane = tid & 63;
  const int cn = lane & 15, kgrp = lane >> 4;
  const int combc = wave * 64;
  const bool isR = combc >= N;
  const ushort* Bh = BT + (isR ? 2 * PLANE : 0);
  const ushort* Bl_ = Bh + PLANE;
  const int cb = combc & (N - 1);
  f32x4 acc[4][4];
  #pragma unroll
  for (int rt = 0; rt < 4; ++rt)
    #pragma unroll
    for (int ct = 0; ct < 4; ++ct) acc[rt][ct] = (f32x4)(0.f);

  #pragma unroll 2
  for (int k0 = 0; k0 < 256; k0 += 32) {
    short8 ah[4], al[4];
    #pragma unroll
    for (int rt = 0; rt < 4; ++rt) {
      int row = rt * 16 + cn;
      int off = row * 512 + (((k0 * 2) + kgrp * 16) ^ ((row & 7) << 4));
      ah[rt] = *(const short8*)((const char*)Ah_s + off);
      al[rt] = *(const short8*)((const char*)Al_s + off);
    }
    const size_t bbase = (size_t)((k0 >> 3) + kgrp) * (N * 8);
    #pragma unroll
    for (int ct = 0; ct < 4; ++ct) {
      const size_t bo = bbase + (size_t)(cb + ct * 16 + cn) * 8;
      short8 bh = *(const short8*)&Bh[bo];
      short8 bl = *(const short8*)&Bl_[bo];
      #pragma unroll
      for (int rt = 0; rt < 4; ++rt) {
        acc[rt][ct] = __builtin_amdgcn_mfma_f32_16x16x32_bf16(ah[rt], bh, acc[rt][ct], 0, 0, 0);
        acc[rt][ct] = __builtin_amdgcn_mfma_f32_16x16x32_bf16(ah[rt], bl, acc[rt][ct], 0, 0, 0);
        acc[rt][ct] = __builtin_amdgcn_mfma_f32_16x16x32_bf16(al[rt], bh, acc[rt][ct], 0, 0, 0);
      }
    }
  }

  // epilogue: C/D layout col=lane&15, row=(lane>>4)*4+reg  [m89 verified]
  #pragma unroll
  for (int ct = 0; ct < 4; ++ct) {
    int cc = cb + ct * 16 + cn;
    #pragma unroll
    for (int rt = 0; rt < 4; ++rt) {
      int crow0 = brow0 + rt * 16 + kgrp * 4;
      #pragma unroll
      for (int j = 0; j < 4; ++j) {
        int rr = crow0 + j;
        if (rr < N_NODES) {
          if (!isR) Clb[(size_t)rr * N + cc] = f2bf(acc[rt][ct][j]);
          else      Crb[(size_t)rr * N + cc] = f2bf(acc[rt][ct][j]);
        }
      }
    }
  }
}

// ---------------- CSR build: histogram -> multi-block scan -> scatter
__global__ void hist_kernel(const int* __restrict__ dsts, int* __restrict__ curs) {
  int i = blockIdx.x * blockDim.x + threadIdx.x;
  if (i >= ET) return;
  int d = (i < N_EDGES) ? dsts[i] : i - N_EDGES;
  atomicAdd(&curs[d], 1);
}

__global__ __launch_bounds__(256) void scan_part(
    const int* __restrict__ curs, int* __restrict__ rows, int* __restrict__ bsum)
{
  __shared__ int tmp[256];
  int t = threadIdx.x;
  int i = blockIdx.x * 256 + t;
  int v = (i < N_NODES) ? curs[i] : 0;
  tmp[t] = v;
  __syncthreads();
  #pragma unroll
  for (int off = 1; off < 256; off <<= 1) {
    int u = (t >= off) ? tmp[t - off] : 0;
    __syncthreads();
    tmp[t] += u;
    __syncthreads();
  }
  if (i < N_NODES) rows[i] = tmp[t] - v;
  if (t == 255) bsum[blockIdx.x] = tmp[255];
}

__global__ __launch_bounds__(256) void scan_bsums(
    const int* __restrict__ bsum, int* __restrict__ boff)
{
  __shared__ int tmp[256];
  int t = threadIdx.x;
  int v = (t < SCAN_BLOCKS) ? bsum[t] : 0;
  tmp[t] = v;
  __syncthreads();
  #pragma unroll
  for (int off = 1; off < 256; off <<= 1) {
    int u = (t >= off) ? tmp[t - off] : 0;
    __syncthreads();
    tmp[t] += u;
    __syncthreads();
  }
  if (t < SCAN_BLOCKS) boff[t] = tmp[t] - v;
}

__global__ __launch_bounds__(256) void scan_apply(
    int* __restrict__ rows, const int* __restrict__ boff, int* __restrict__ curs)
{
  int i = blockIdx.x * 256 + threadIdx.x;
  if (i < N_NODES) {
    int r = rows[i] + boff[blockIdx.x];
    rows[i] = r;
    curs[i] = r;
  }
  if (i == 0) rows[N_NODES] = ET;
}

__global__ void scatter_kernel(const int* __restrict__ srcs, const int* __restrict__ dsts,
                               int* __restrict__ curs, int* __restrict__ esrc) {
  int i = blockIdx.x * blockDim.x + threadIdx.x;
  if (i >= ET) return;
  int s, d;
  if (i < N_EDGES) { s = srcs[i]; d = dsts[i]; } else { s = d = i - N_EDGES; }
  int pos = atomicAdd(&curs[d], 1);
  esrc[pos] = s;
}

// ---------------- flash pass, D=256 (4 heads): R7 structure — one wave per
// dst, scalar score math, ushort4 xl gathers, 4-edge unroll. xr in bf16.
__global__ __launch_bounds__(256) void flash256(
    const ushort* __restrict__ xl, const ushort* __restrict__ xr,
    const float* __restrict__ att, const int* __restrict__ rows,
    const int* __restrict__ esrc, float* __restrict__ out)
{
  int d = blockIdx.x * 4 + (threadIdx.x >> 6);
  if (d >= N_NODES) return;
  int lane = threadIdx.x & 63;
  int beg = rows[d], end = rows[d + 1];
  ushort4 ur = *(const ushort4*)&xr[(size_t)d * 256 + lane * 4];
  float xq0 = bf2f(ur.x), xq1 = bf2f(ur.y), xq2 = bf2f(ur.z), xq3 = bf2f(ur.w);
  float4 w = *(const float4*)&att[lane * 4];
  auto score = [&](float b0, float b1, float b2, float b3) {
    float v0 = b0 + xq0, v1 = b1 + xq1, v2 = b2 + xq2, v3 = b3 + xq3;
    v0 = v0 > 0.f ? v0 : 0.2f * v0;
    v1 = v1 > 0.f ? v1 : 0.2f * v1;
    v2 = v2 > 0.f ? v2 : 0.2f * v2;
    v3 = v3 > 0.f ? v3 : 0.2f * v3;
    return fmaf(v0, w.x, fmaf(v1, w.y, fmaf(v2, w.z, v3 * w.w)));
  };
  float m = -INFINITY, s = 0.f;
  float a0 = 0.f, a1 = 0.f, a2 = 0.f, a3 = 0.f;
  int p = beg;
  for (; p + 4 <= end; p += 4) {
    int s1 = esrc[p], s2 = esrc[p + 1], s3 = esrc[p + 2], s4 = esrc[p + 3];
    ushort4 u1 = *(const ushort4*)&xl[(size_t)s1 * 256 + lane * 4];
    ushort4 u2 = *(const ushort4*)&xl[(size_t)s2 * 256 + lane * 4];
    ushort4 u3 = *(const ushort4*)&xl[(size_t)s3 * 256 + lane * 4];
    ushort4 u4 = *(const ushort4*)&xl[(size_t)s4 * 256 + lane * 4];
    float b10 = bf2f(u1.x), b11 = bf2f(u1.y), b12 = bf2f(u1.z), b13 = bf2f(u1.w);
    float b20 = bf2f(u2.x), b21 = bf2f(u2.y), b22 = bf2f(u2.z), b23 = bf2f(u2.w);
    float b30 = bf2f(u3.x), b31 = bf2f(u3.y), b32 = bf2f(u3.z), b33 = bf2f(u3.w);
    float b40 = bf2f(u4.x), b41 = bf2f(u4.y), b42 = bf2f(u4.z), b43 = bf2f(u4.w);
    float e1 = score(b10, b11, b12, b13);
    float e2 = score(b20, b21, b22, b23);
    float e3 = score(b30, b31, b32, b33);
    float e4 = score(b40, b41, b42, b43);
    e1 += __shfl_xor(e1, 1); e2 += __shfl_xor(e2, 1);
    e3 += __shfl_xor(e3, 1); e4 += __shfl_xor(e4, 1);
    e1 += __shfl_xor(e1, 2); e2 += __shfl_xor(e2, 2);
    e3 += __shfl_xor(e3, 2); e4 += __shfl_xor(e4, 2);
    e1 += __shfl_xor(e1, 4); e2 += __shfl_xor(e2, 4);
    e3 += __shfl_xor(e3, 4); e4 += __shfl_xor(e4, 4);
    e1 += __shfl_xor(e1, 8); e2 += __shfl_xor(e2, 8);
    e3 += __shfl_xor(e3, 8); e4 += __shfl_xor(e4, 8);
    float mn = fmaxf(fmaxf(m, fmaxf(e1, e2)), fmaxf(e3, e4));
    float f = __expf(m - mn);
    float p1 = __expf(e1 - mn);
    float p2 = __expf(e2 - mn);
    float p3 = __expf(e3 - mn);
    float p4 = __expf(e4 - mn);
    s = s * f + ((p1 + p2) + (p3 + p4));
    a0 = fmaf(a0, f, fmaf(p1, b10, fmaf(p2, b20, fmaf(p3, b30, p4 * b40))));
    a1 = fmaf(a1, f, fmaf(p1, b11, fmaf(p2, b21, fmaf(p3, b31, p4 * b41))));
    a2 = fmaf(a2, f, fmaf(p1, b12, fmaf(p2, b22, fmaf(p3, b32, p4 * b42))));
    a3 = fmaf(a3, f, fmaf(p1, b13, fmaf(p2, b23, fmaf(p3, b33, p4 * b43))));
    m = mn;
  }
  for (; p < end; ++p) {
    int s1 = esrc[p];
    ushort4 u1 = *(const ushort4*)&xl[(size_t)s1 * 256 + lane * 4];
    float b10 = bf2f(u1.x), b11 = bf2f(u1.y), b12 = bf2f(u1.z), b13 = bf2f(u1.w);
    float e1 = score(b10, b11, b12, b13);
    e1 += __shfl_xor(e1, 1);
    e1 += __shfl_xor(e1, 2);
    e1 += __shfl_xor(e1, 4);
    e1 += __shfl_xor(e1, 8);
    float mn = fmaxf(m, e1);
    float f = __expf(m - mn);
    float p1 = __expf(e1 - mn);
    s = fmaf(s, f, p1);
    a0 = fmaf(a0, f, p1 * b10);
    a1 = fmaf(a1, f, p1 * b11);
    a2 = fmaf(a2, f, p1 * b12);
    a3 = fmaf(a3, f, p1 * b13);
    m = mn;
  }
  float inv = 1.f / (s + 1e-16f);
  *(float4*)&out[(size_t)d * 256 + lane * 4] =
      make_float4(a0 * inv, a1 * inv, a2 * inv, a3 * inv);
}

// ---------------- flash pass, D=64 (1 head): 8 lanes per dst (8 ch each,
// 16B gathers), 8 dsts per wave. xr in bf16.
__global__ __launch_bounds__(256) void flash64(
    const ushort* __restrict__ xl, const ushort* __restrict__ xr,
    const float* __restrict__ att, const int* __restrict__ rows,
    const int* __restrict__ esrc, float* __restrict__ out)
{
  const int wave = threadIdx.x >> 6, lane = threadIdx.x & 63;
  const int di = lane >> 3, sl = lane & 7;
  const int d = blockIdx.x * 32 + wave * 8 + di;
  const bool valid = d < N_NODES;
  const int dc = valid ? d : N_NODES - 1;
  const int ch = sl * 8;
  ushort8 uxr = *(const ushort8*)&xr[(size_t)dc * 64 + ch];
  float4 wa = *(const float4*)&att[ch];
  float4 wb = *(const float4*)&att[ch + 4];
  f32x2 xr0 = {bf2f(uxr[0]), bf2f(uxr[1])}, xr1 = {bf2f(uxr[2]), bf2f(uxr[3])};
  f32x2 xr2 = {bf2f(uxr[4]), bf2f(uxr[5])}, xr3 = {bf2f(uxr[6]), bf2f(uxr[7])};
  f32x2 w0 = {wa.x, wa.y}, w1 = {wa.z, wa.w}, w2 = {wb.x, wb.y}, w3 = {wb.z, wb.w};
  int beg = rows[dc], end = rows[dc + 1];
  float m = -INFINITY, s = 0.f;
  f32x2 a0 = {0.f, 0.f}, a1 = {0.f, 0.f}, a2 = {0.f, 0.f}, a3 = {0.f, 0.f};

  auto loadb = [&](int src, f32x2 b[4]) {
    ushort8 u = *(const ushort8*)&xl[(size_t)src * 64 + ch];
    b[0] = f32x2{bf2f(u[0]), bf2f(u[1])};
    b[1] = f32x2{bf2f(u[2]), bf2f(u[3])};
    b[2] = f32x2{bf2f(u[4]), bf2f(u[5])};
    b[3] = f32x2{bf2f(u[6]), bf2f(u[7])};
  };
  auto scoreP = [&](const f32x2 b[4]) -> float {
    f32x2 v0 = b[0] + xr0, v1 = b[1] + xr1, v2 = b[2] + xr2, v3 = b[3] + xr3;
    v0 = emax2(v0, v0 * 0.2f);
    v1 = emax2(v1, v1 * 0.2f);
    v2 = emax2(v2, v2 * 0.2f);
    v3 = emax2(v3, v3 * 0.2f);
    f32x2 dd = (v0 * w0 + v1 * w1) + (v2 * w2 + v3 * w3);
    return dd.x + dd.y;
  };
  auto one_edge = [&](int src) {
    f32x2 b[4];
    loadb(src, b);
    float e = scoreP(b);
    e += __shfl_xor(e, 1);
    e += __shfl_xor(e, 2);
    e += __shfl_xor(e, 4);
    float mn = fmaxf(m, e);
    float f = __expf(m - mn);
    float pe = __expf(e - mn);
    s = s * f + pe;
    a0 = a0 * f + b[0] * pe;
    a1 = a1 * f + b[1] * pe;
    a2 = a2 * f + b[2] * pe;
    a3 = a3 * f + b[3] * pe;
    m = mn;
  };

  int p = beg;
  int hd = min(end, (beg + 3) & ~3);
  for (; p < hd; ++p) one_edge(esrc[p]);
  for (; p + 4 <= end; p += 4) {
    int4 sv = *(const int4*)&esrc[p];
    f32x2 b1[4], b2[4], b3[4], b4[4];
    loadb(sv.x, b1);
    loadb(sv.y, b2);
    loadb(sv.z, b3);
    loadb(sv.w, b4);
    float e1 = scoreP(b1);
    float e2 = scoreP(b2);
    float e3 = scoreP(b3);
    float e4 = scoreP(b4);
    e1 += __shfl_xor(e1, 1); e2 += __shfl_xor(e2, 1);
    e3 += __shfl_xor(e3, 1); e4 += __shfl_xor(e4, 1);
    e1 += __shfl_xor(e1, 2); e2 += __shfl_xor(e2, 2);
    e3 += __shfl_xor(e3, 2); e4 += __shfl_xor(e4, 2);
    e1 += __shfl_xor(e1, 4); e2 += __shfl_xor(e2, 4);
    e3 += __shfl_xor(e3, 4); e4 += __shfl_xor(e4, 4);
    float mn = fmaxf(fmaxf(m, fmaxf(e1, e2)), fmaxf(e3, e4));
    float f = __expf(m - mn);
    float p1 = __expf(e1 - mn);
    float p2 = __expf(e2 - mn);
    float p3 = __expf(e3 - mn);
    float p4 = __expf(e4 - mn);
    s = s * f + ((p1 + p2) + (p3 + p4));
    a0 = a0 * f + ((b1[0] * p1 + b2[0] * p2) + (b3[0] * p3 + b4[0] * p4));
    a1 = a1 * f + ((b1[1] * p1 + b2[1] * p2) + (b3[1] * p3 + b4[1] * p4));
    a2 = a2 * f + ((b1[2] * p1 + b2[2] * p2) + (b3[2] * p3 + b4[2] * p4));
    a3 = a3 * f + ((b1[3] * p1 + b2[3] * p2) + (b3[3] * p3 + b4[3] * p4));
    m = mn;
  }
  for (; p < end; ++p) one_edge(esrc[p]);

  if (valid) {
    float inv = 1.f / (s + 1e-16f);
    *(float4*)&out[(size_t)d * 64 + ch] =
        make_float4(a0.x * inv, a0.y * inv, a1.x * inv, a1.y * inv);
    *(float4*)&out[(size_t)d * 64 + ch + 4] =
        make_float4(a2.x * inv, a2.y * inv, a3.x * inv, a3.y * inv);
  }
}

// ---------------- BN statistics (per-channel sum / sumsq)
template<int D_, int RPB>
__global__ __launch_bounds__(256) void bn_stats(const float* __restrict__ h,
    float* __restrict__ gsum, float* __restrict__ gsumsq, int nrows)
{
  constexpr int RG = 256 / D_;
  int c = threadIdx.x % D_;
  int rg = threadIdx.x / D_;
  int r0 = blockIdx.x * RPB;
  float s = 0.f, sq = 0.f;
  int rend = min(r0 + RPB, nrows);
  for (int r = r0 + rg; r < rend; r += RG) {
    float v = h[(size_t)r * D_ + c];
    s += v;
    sq = fmaf(v, v, sq);
  }
  atomicAdd(&gsum[c], s);
  atomicAdd(&gsumsq[c], sq);
}

// ---------------- fused pooling (BN finalize+apply inline) + classifier MLP.
__global__ __launch_bounds__(256) void pool_mlp(
    const float* __restrict__ h3, const int* __restrict__ batch,
    const float* __restrict__ gsum, const float* __restrict__ gsumsq,
    const float* __restrict__ g3, const float* __restrict__ be3,
    const float* __restrict__ Wc1, const float* __restrict__ bc1,
    const float* __restrict__ Wc2, const float* __restrict__ bc2,
    float* __restrict__ outp)
{
  int g = blockIdx.x;
  int t = threadIdx.x;
  int lane = t & 63, w = t >> 6;
  int lo, hi;
  {
    int a = 0, b = N_NODES;
    while (a < b) { int mid = (a + b) >> 1; if (batch[mid] < g) a = mid + 1; else b = mid; }
    lo = a;
    b = N_NODES;
    while (a < b) { int mid = (a + b) >> 1; if (batch[mid] < g + 1) a = mid + 1; else b = mid; }
    hi = a;
  }
  const float invn = 1.0f / (float)N_NODES;
  float mu = gsum[lane] * invn;
  float var = gsumsq[lane] * invn - mu * mu;
  float scl = g3[lane] * rsqrtf(var + 1e-5f);
  float shf = be3[lane] - mu * scl;
  float s = 0.f, mx = -INFINITY;
  for (int r = lo + w; r < hi; r += 4) {
    float v = fmaf(h3[(size_t)r * 64 + lane], scl, shf);
    s += v;
    mx = fmaxf(mx, v);
  }
  __shared__ float ssum[4][64];
  __shared__ float smax[4][64];
  __shared__ float pooled[128];
  ssum[w][lane] = s;
  smax[w][lane] = mx;
  __syncthreads();
  if (w == 0) {
    float tot = ssum[0][lane] + ssum[1][lane] + ssum[2][lane] + ssum[3][lane];
    float m4 = fmaxf(fmaxf(smax[0][lane], smax[1][lane]),
                     fmaxf(smax[2][lane], smax[3][lane]));
    float cnt = (float)(hi - lo);
    pooled[lane] = tot / fmaxf(cnt, 1.f);
    pooled[64 + lane] = m4;
  }
  __syncthreads();
  if (w == 0) {
    float a = bc1[lane];
    #pragma unroll 8
    for (int k = 0; k < 128; ++k) a = fmaf(pooled[k], Wc1[k * 64 + lane], a);
    a = fmaxf(a, 0.f);
    float v = a * Wc2[lane];
    v += __shfl_xor(v, 1);
    v += __shfl_xor(v, 2);
    v += __shfl_xor(v, 4);
    v += __shfl_xor(v, 8);
    v += __shfl_xor(v, 16);
    v += __shfl_xor(v, 32);
    if (lane == 0) outp[g] = v + bc2[0];
  }
}

extern "C" void kernel_launch(void* const* d_in, const int* in_sizes, int n_in,
                              void* d_out, int out_size, void* d_ws, size_t ws_size,
                              hipStream_t stream)
{
  const float* x    = (const float*)d_in[0];
  const int*   ei   = (const int*)d_in[1];
  const int*   batch= (const int*)d_in[2];
  const float* Wl1  = (const float*)d_in[3];
  const float* Wr1  = (const float*)d_in[4];
  const float* att1 = (const float*)d_in[5];
  // b1/b2/b3 cancel in the following BatchNorm -> unused
  const float* g1   = (const float*)d_in[7];
  const float* be1  = (const float*)d_in[8];
  const float* Wl2  = (const float*)d_in[9];
  const float* Wr2  = (const float*)d_in[10];
  const float* att2 = (const float*)d_in[11];
  const float* g2   = (const float*)d_in[13];
  const float* be2  = (const float*)d_in[14];
  const float* Wl3  = (const float*)d_in[15];
  const float* Wr3  = (const float*)d_in[16];
  const float* att3 = (const float*)d_in[17];
  const float* g3   = (const float*)d_in[19];
  const float* be3  = (const float*)d_in[20];
  const float* Wc1  = (const float*)d_in[21];
  const float* bc1  = (const float*)d_in[22];
  const float* Wc2  = (const float*)d_in[23];
  const float* bc2  = (const float*)d_in[24];

  const int* srcs = ei;
  const int* dsts = ei + N_EDGES;

  float* ws = (float*)d_ws;
  size_t o = 0;
  ushort* XLB = (ushort*)(ws + o); o += (size_t)N_NODES * HIDD / 2;  // bf16 xl
  ushort* XRB = (ushort*)(ws + o); o += (size_t)N_NODES * HIDD / 2;  // bf16 xr
  float* Hb = ws + o;            o += (size_t)N_NODES * HIDD;
  ushort* BT2 = (ushort*)(ws + o); o += (size_t)4 * 32 * 256 * 8 / 2;   // 2 mats x 2 halves
  ushort* BT3 = (ushort*)(ws + o); o += (size_t)4 * 32 * 64 * 8 / 2;
  int* ESRC = (int*)(ws + o);    o += ET;
  int* ROWS = (int*)(ws + o);    o += N_NODES + 1;
  int* CURS = (int*)(ws + o);    o += N_NODES;
  int* BSUM = (int*)(ws + o);    o += SCAN_BLOCKS;
  int* BOFF = (int*)(ws + o);    o += SCAN_BLOCKS;
  float* GS  = ws + o;           o += 256;
  float* GSQ = ws + o;           o += 256;

  const int ROW_BLOCKS = (N_NODES + 63) / 64;
  const int DST_BLOCKS = (N_NODES + 3) / 4;
  constexpr int PLANE2 = 32 * 256 * 8;
  constexpr int PLANE3 = 32 * 64 * 8;

  // ================= weight transpose/split (independent; run once up front)
  convertB<256, 256><<<(65536 + 255) / 256, 256, 0, stream>>>(Wl2, BT2);
  convertB<256, 256><<<(65536 + 255) / 256, 256, 0, stream>>>(Wr2, BT2 + 2 * PLANE2);
  convertB<256, 64><<<(16384 + 255) / 256, 256, 0, stream>>>(Wl3, BT3);
  convertB<256, 64><<<(16384 + 255) / 256, 256, 0, stream>>>(Wr3, BT3 + 2 * PLANE3);

  // ================= CSR build (reused by all 3 layers) =================
  hipMemsetAsync(CURS, 0, N_NODES * 4, stream);
  hist_kernel<<<(ET + 255) / 256, 256, 0, stream>>>(dsts, CURS);
  scan_part<<<SCAN_BLOCKS, 256, 0, stream>>>(CURS, ROWS, BSUM);
  scan_bsums<<<1, 256, 0, stream>>>(BSUM, BOFF);
  scan_apply<<<SCAN_BLOCKS, 256, 0, stream>>>(ROWS, BOFF, CURS);
  scatter_kernel<<<(ET + 255) / 256, 256, 0, stream>>>(srcs, dsts, CURS, ESRC);

  // ================= layer 1 (16 -> 4x64, concat): fp32 vector GEMM ======
  gemm_dual<16, 256><<<dim3(ROW_BLOCKS, 4), 256, 0, stream>>>(
      x, Wl1, Wr1, XLB, XRB, N_NODES);
  flash256<<<DST_BLOCKS, 256, 0, stream>>>(XLB, XRB, att1, ROWS, ESRC, Hb);
  hipMemsetAsync(GS, 0, 512 * 4, stream);
  bn_stats<256, 64><<<ROW_BLOCKS, 256, 0, stream>>>(Hb, GS, GSQ, N_NODES);

  // ================= layer 2 (256 -> 4x64): fully-fused BN+ELU+MFMA GEMM ==
  gemm_fused<256><<<ROW_BLOCKS, 512, 0, stream>>>(
      Hb, GS, GSQ, g1, be1, BT2, XLB, XRB);
  flash256<<<DST_BLOCKS, 256, 0, stream>>>(XLB, XRB, att2, ROWS, ESRC, Hb);
  hipMemsetAsync(GS, 0, 512 * 4, stream);
  bn_stats<256, 64><<<ROW_BLOCKS, 256, 0, stream>>>(Hb, GS, GSQ, N_NODES);

  // ================= layer 3 (256 -> 64, 1 head): fused MFMA GEMM ========
  gemm_fused<64><<<ROW_BLOCKS, 128, 0, stream>>>(
      Hb, GS, GSQ, g2, be2, BT3, XLB, XRB);
  flash64<<<(N_NODES + 31) / 32, 256, 0, stream>>>(XLB, XRB, att3, ROWS, ESRC, Hb);
  hipMemsetAsync(GS, 0, 512 * 4, stream);
  bn_stats<64, 256><<<(N_NODES + 255) / 256, 256, 0, stream>>>(Hb, GS, GSQ, N_NODES);

  // ================= fused pooling (BN inline) + classifier ==============
  pool_mlp<<<N_GRAPHS, 256, 0, stream>>>(Hb, batch, GS, GSQ, g3, be3,
                                         Wc1, bc1, Wc2, bc2, (float*)d_out);
}